// Round 3
// baseline (1409.256 us; speedup 1.0000x reference)
//
#include <hip/hip_runtime.h>

#define N_NODES 100000
#define N_EDGES 1200000
#define HDIM 64
#define NUM_RELS 24
#define NPB 50                      // nodes per dst-bin
#define NBINS 2000                  // NPB * NBINS == N_NODES exactly
#define NKEYS (NBINS * NUM_RELS)    // 48000 sort buckets, key = bin*24 + rel

// ---------------- histogram over 48000 keys + degree ----------------
__global__ void hist_kernel(const int* __restrict__ dst, const int* __restrict__ rel,
                            int* __restrict__ cnt, float* __restrict__ deg) {
    for (int i = blockIdx.x * blockDim.x + threadIdx.x; i < N_EDGES;
         i += gridDim.x * blockDim.x) {
        int d = dst[i];
        int key = (d / NPB) * NUM_RELS + rel[i];
        atomicAdd(&cnt[key], 1);        // 1.2M atomics over 48K addrs: ~25/addr
        atomicAdd(&deg[d], 1.0f);
    }
}

// ---------------- exclusive scan of 48000 bins (one block) ----------------
__global__ __launch_bounds__(256) void scan_kernel(const int* __restrict__ cnt,
                                                   int* __restrict__ ofs,
                                                   int* __restrict__ ofs2) {
    __shared__ int psum[256];
    const int PER = (NKEYS + 255) / 256;  // 188
    const int t = threadIdx.x;
    const int lo = t * PER;
    int s = 0;
    for (int k = 0; k < PER; ++k) {
        int idx = lo + k;
        if (idx < NKEYS) s += cnt[idx];
    }
    psum[t] = s;
    __syncthreads();
    if (t == 0) {
        int acc = 0;
        for (int i = 0; i < 256; ++i) { int v = psum[i]; psum[i] = acc; acc += v; }
    }
    __syncthreads();
    int acc = psum[t];
    for (int k = 0; k < PER; ++k) {
        int idx = lo + k;
        if (idx < NKEYS) { ofs[idx] = acc; ofs2[idx] = acc; acc += cnt[idx]; }
    }
    if (t == 255) ofs[NKEYS] = acc;  // == N_EDGES
}

// ---------------- scatter into key-sorted order, packed u64 ----------------
// pack: src (17b) | dst << 17 (17b) | rel << 34 (5b)
__global__ void scatter_kernel(const int* __restrict__ src, const int* __restrict__ dst,
                               const int* __restrict__ rel, int* __restrict__ ofs2,
                               unsigned long long* __restrict__ epack) {
    for (int i = blockIdx.x * blockDim.x + threadIdx.x; i < N_EDGES;
         i += gridDim.x * blockDim.x) {
        int s = src[i], d = dst[i], r = rel[i];
        int key = (d / NPB) * NUM_RELS + r;
        int p = atomicAdd(&ofs2[key], 1);
        epack[p] = (unsigned long long)(unsigned)s |
                   ((unsigned long long)(unsigned)d << 17) |
                   ((unsigned long long)(unsigned)r << 34);
    }
}

// ---------------- per-bin transform + LDS aggregate + mean/relu writeout ----
// One block per dst-bin. Edges are (bin, rel)-sorted: waves keep one W column
// set in VGPRs per rel-segment (asm-pinned so the compiler can't remat the
// loads), accumulate into LDS (CU-local atomics, no XCD coherence tax), then
// write mean+relu directly -- zero global atomics, no finalize pass.
__global__ __launch_bounds__(256) void edge_kernel(
    const float* __restrict__ hin, const unsigned long long* __restrict__ epack,
    const int* __restrict__ ofs, const float* __restrict__ W,
    const float* __restrict__ deg, float* __restrict__ out) {
    __shared__ float agg[NPB * HDIM];  // 12.8 KB

    const int bin = blockIdx.x;
    const int node_lo = bin * NPB;
    const int lane = threadIdx.x & 63;
    const int wv = threadIdx.x >> 6;  // 0..3

    for (int i = threadIdx.x; i < NPB * HDIM; i += 256) agg[i] = 0.f;
    __syncthreads();

    const int elo = ofs[bin * NUM_RELS];
    const int ehi = ofs[bin * NUM_RELS + NUM_RELS];
    const int per = (ehi - elo + 3) >> 2;
    int lo = elo + wv * per;
    int hi = lo + per;
    if (hi > ehi) hi = ehi;

    float wcol[HDIM];
    int cur_r = -1;
    for (int e = lo; e < hi; ++e) {
        unsigned long long u = epack[e];  // wave-uniform address
        unsigned ulo = (unsigned)__builtin_amdgcn_readfirstlane((int)(u & 0xffffffffULL));
        unsigned uhi = (unsigned)__builtin_amdgcn_readfirstlane((int)(u >> 32));
        int s = (int)(ulo & 0x1ffffu);
        int d = (int)((ulo >> 17) | ((uhi & 3u) << 15));
        int r = (int)((uhi >> 2) & 31u);
        if (r != cur_r) {  // wave-uniform; ~6-8 reloads per wave chunk
            cur_r = r;
            const float* wp = W + (size_t)r * (HDIM * HDIM) + lane;
#pragma unroll
            for (int k = 0; k < HDIM; ++k) wcol[k] = wp[(size_t)k * HDIM];
#pragma unroll
            for (int k = 0; k < HDIM; ++k) asm volatile("" : "+v"(wcol[k]));  // pin to VGPR
        }
        const float4* hp = (const float4*)(hin + (size_t)s * HDIM);
        float acc = 0.f;
#pragma unroll
        for (int q = 0; q < HDIM / 4; ++q) {
            float4 hv = hp[q];
            acc = fmaf(hv.x, wcol[4 * q + 0], acc);
            acc = fmaf(hv.y, wcol[4 * q + 1], acc);
            acc = fmaf(hv.z, wcol[4 * q + 2], acc);
            acc = fmaf(hv.w, wcol[4 * q + 3], acc);
        }
        atomicAdd(&agg[(d - node_lo) * HDIM + lane], acc);  // LDS atomic
    }
    __syncthreads();

    // writeout: mean + relu, coalesced float4
    const float4* ag4 = (const float4*)agg;
    float4* out4 = (float4*)(out + (size_t)node_lo * HDIM);
    for (int i = threadIdx.x; i < NPB * HDIM / 4; i += 256) {
        int row = i >> 4;  // 16 float4 per node row
        float inv = 1.0f / fmaxf(deg[node_lo + row], 1.0f);
        float4 v = ag4[i];
        v.x = fmaxf(v.x * inv, 0.f);
        v.y = fmaxf(v.y * inv, 0.f);
        v.z = fmaxf(v.z * inv, 0.f);
        v.w = fmaxf(v.w * inv, 0.f);
        out4[i] = v;
    }
}

extern "C" void kernel_launch(void* const* d_in, const int* in_sizes, int n_in,
                              void* d_out, int out_size, void* d_ws, size_t ws_size,
                              hipStream_t stream) {
    const float* h = (const float*)d_in[0];
    const int* src = (const int*)d_in[1];
    const int* dst = (const int*)d_in[2];
    const int* rel = (const int*)d_in[3];
    const float* W1 = (const float*)d_in[4];
    const float* W2 = (const float*)d_in[5];
    float* out = (float*)d_out;

    // ---- workspace layout ----
    char* w = (char*)d_ws;
    unsigned long long* epack = (unsigned long long*)w;        // 9.6 MB
    int* cnt = (int*)(w + (size_t)N_EDGES * 8);                // NKEYS+1
    int* ofs = cnt + (NKEYS + 4);                              // NKEYS+1
    int* ofs2 = ofs + (NKEYS + 4);                             // NKEYS
    float* deg = (float*)(ofs2 + (NKEYS + 4));                 // N_NODES
    float* h1 = deg + N_NODES;                                 // 25.6 MB

    hipMemsetAsync(cnt, 0, (NKEYS + 4) * sizeof(int), stream);
    hipMemsetAsync(deg, 0, N_NODES * sizeof(float), stream);

    // ---- counting sort by (dst-bin, rel) + degree ----
    hist_kernel<<<1024, 256, 0, stream>>>(dst, rel, cnt, deg);
    scan_kernel<<<1, 256, 0, stream>>>(cnt, ofs, ofs2);
    scatter_kernel<<<1024, 256, 0, stream>>>(src, dst, rel, ofs2, epack);

    // ---- layer 1: h -> h1 ----
    edge_kernel<<<NBINS, 256, 0, stream>>>(h, epack, ofs, W1, deg, h1);
    // ---- layer 2: h1 -> out ----
    edge_kernel<<<NBINS, 256, 0, stream>>>(h1, epack, ofs, W2, deg, out);
}

// Round 4
// 1392.465 us; speedup vs baseline: 1.0121x; 1.0121x over previous
//
#include <hip/hip_runtime.h>

#define N_NODES 100000
#define N_EDGES 1200000
#define HDIM 64
#define NUM_RELS 24
#define NPB 50                       // nodes per dst-bin
#define NBINS 2000                   // NPB * NBINS == N_NODES
#define NKEYS (NBINS * NUM_RELS)     // 48000, key = bin*24 + rel
#define NCOLS (NUM_RELS * HDIM)      // 1536

typedef short bf16x8 __attribute__((ext_vector_type(8)));
typedef float f32x4 __attribute__((ext_vector_type(4)));

__device__ __forceinline__ unsigned short f2bf(float f) {
    unsigned u = __builtin_bit_cast(unsigned, f);
    u += 0x7fffu + ((u >> 16) & 1u);            // round-to-nearest-even
    return (unsigned short)(u >> 16);
}
__device__ __forceinline__ float bf2f(unsigned short b) {
    return __builtin_bit_cast(float, (unsigned)b << 16);
}

// ---------------- prep: h f32 -> bf16 ----------------
__global__ void prep_h(const float* __restrict__ h, unsigned short* __restrict__ hb) {
    int i = blockIdx.x * blockDim.x + threadIdx.x;  // over float4s
    if (i >= N_NODES * HDIM / 4) return;
    float4 v = ((const float4*)h)[i];
    ushort4 o;
    o.x = f2bf(v.x); o.y = f2bf(v.y); o.z = f2bf(v.z); o.w = f2bf(v.w);
    ((ushort4*)hb)[i] = o;
}

// ---------------- prep: W -> Bt bf16, Bt[r*64+j][k] = W[r][k][j] ----------------
__global__ void prep_w(const float* __restrict__ W1, const float* __restrict__ W2,
                       unsigned short* __restrict__ Bt1, unsigned short* __restrict__ Bt2) {
    int idx = blockIdx.x * blockDim.x + threadIdx.x;
    if (idx >= NCOLS * HDIM) return;
    int row = idx >> 6;        // r*64 + j
    int k = idx & 63;
    int r = row >> 6, j = row & 63;
    int widx = (r << 12) + (k << 6) + j;
    Bt1[idx] = f2bf(W1[widx]);
    Bt2[idx] = f2bf(W2[widx]);
}

// ---------------- histogram over 48000 keys + degree ----------------
__global__ void hist_kernel(const int* __restrict__ dst, const int* __restrict__ rel,
                            int* __restrict__ cnt, float* __restrict__ deg) {
    for (int i = blockIdx.x * blockDim.x + threadIdx.x; i < N_EDGES;
         i += gridDim.x * blockDim.x) {
        unsigned d = (unsigned)dst[i];
        unsigned key = (d / NPB) * NUM_RELS + (unsigned)rel[i];
        atomicAdd(&cnt[key], 1);
        atomicAdd(&deg[d], 1.0f);
    }
}

// ---------------- 3-stage parallel exclusive scan over 48000 ----------------
__global__ __launch_bounds__(256) void scan1(const int* __restrict__ cnt, int* __restrict__ bsum) {
    __shared__ int sd[256];
    int g = blockIdx.x * 256 + threadIdx.x;
    sd[threadIdx.x] = (g < NKEYS) ? cnt[g] : 0;
    __syncthreads();
    for (int s = 128; s > 0; s >>= 1) {
        if (threadIdx.x < s) sd[threadIdx.x] += sd[threadIdx.x + s];
        __syncthreads();
    }
    if (threadIdx.x == 0) bsum[blockIdx.x] = sd[0];
}
__global__ void scan2(const int* __restrict__ bsum, int* __restrict__ bbase, int* __restrict__ ofs) {
    if (threadIdx.x == 0 && blockIdx.x == 0) {
        int acc = 0;
        for (int i = 0; i < 188; ++i) { bbase[i] = acc; acc += bsum[i]; }
        ofs[NKEYS] = acc;  // == N_EDGES
    }
}
__global__ __launch_bounds__(256) void scan3(const int* __restrict__ cnt, const int* __restrict__ bbase,
                                             int* __restrict__ ofs, int* __restrict__ ofs2) {
    __shared__ int sd[256];
    int g = blockIdx.x * 256 + threadIdx.x;
    sd[threadIdx.x] = (g < NKEYS) ? cnt[g] : 0;
    __syncthreads();
    if (threadIdx.x == 0) {
        int acc = bbase[blockIdx.x];
        for (int i = 0; i < 256; ++i) { int t = sd[i]; sd[i] = acc; acc += t; }
    }
    __syncthreads();
    if (g < NKEYS) { ofs[g] = sd[threadIdx.x]; ofs2[g] = sd[threadIdx.x]; }
}

// ---------------- scatter into key-sorted order, packed u32 ----------------
// pack: src (17b) | rel << 17 (5b) | dloc << 22 (6b)
__global__ void scatter_kernel(const int* __restrict__ src, const int* __restrict__ dst,
                               const int* __restrict__ rel, int* __restrict__ ofs2,
                               unsigned* __restrict__ epack) {
    for (int i = blockIdx.x * blockDim.x + threadIdx.x; i < N_EDGES;
         i += gridDim.x * blockDim.x) {
        unsigned s = (unsigned)src[i], d = (unsigned)dst[i], r = (unsigned)rel[i];
        unsigned b = d / NPB;
        unsigned dl = d - b * NPB;
        int p = atomicAdd(&ofs2[b * NUM_RELS + r], 1);
        epack[p] = s | (r << 17) | (dl << 22);
    }
}

// ---------------- GEMM: hw[m][n] = sum_k A[m][k] * Bt[n][k], bf16 MFMA ----------------
// Operand-swapped mfma: D[n][m] with a_frag = Bt rows (n), b_frag = A rows (m).
// C/D layout: col(lane&15) = m, rows = n0 + (lane>>4)*4 + reg -> 4 consecutive n
// per lane -> direct 8B bf16 store, no LDS bounce.
__global__ __launch_bounds__(256) void gemm_kernel(
    const unsigned short* __restrict__ A, const unsigned short* __restrict__ Bt,
    unsigned short* __restrict__ hw, int r0, int Wp) {
    const int lane = threadIdx.x & 63;
    const int w = threadIdx.x >> 6;
    const int li = lane & 15, kq = lane >> 4;
    const int m = blockIdx.x * 16 + li;

    bf16x8 b0 = *(const bf16x8*)(A + m * 64 + kq * 8);        // k 0..31 slice
    bf16x8 b1 = *(const bf16x8*)(A + m * 64 + 32 + kq * 8);   // k 32..63 slice

    const int ncols = Wp >> 2;        // cols per wave
    const int ntiles = ncols >> 4;
    const int nbase = w * ncols;
    for (int t = 0; t < ntiles; ++t) {
        const int n0 = nbase + t * 16;
        const unsigned short* btp = Bt + (size_t)(r0 * 64 + n0 + li) * 64 + kq * 8;
        bf16x8 a0 = *(const bf16x8*)(btp);
        bf16x8 a1 = *(const bf16x8*)(btp + 32);
        f32x4 acc = {0.f, 0.f, 0.f, 0.f};
        acc = __builtin_amdgcn_mfma_f32_16x16x32_bf16(a0, b0, acc, 0, 0, 0);
        acc = __builtin_amdgcn_mfma_f32_16x16x32_bf16(a1, b1, acc, 0, 0, 0);
        ushort4 o;
        o.x = f2bf(acc[0]); o.y = f2bf(acc[1]); o.z = f2bf(acc[2]); o.w = f2bf(acc[3]);
        *(ushort4*)(hw + (size_t)m * Wp + n0 + kq * 4) = o;
    }
}

// ---------------- gather + LDS aggregate + (mean/relu) writeout ----------------
// One block per dst-bin; 16 lane-groups of 16, each group fetches one edge's
// 128B hw row cooperatively (8B/lane). FIRST: no carry-in. OUT: 0 = store
// partial to aggG, 1 = write bf16 h1, 2 = write f32 final.
template <bool FIRST, int OUT>
__global__ __launch_bounds__(256) void agg_kernel(
    const unsigned short* __restrict__ hw, const unsigned* __restrict__ epack,
    const int* __restrict__ ofs, const float* __restrict__ deg,
    float* __restrict__ aggG, void* __restrict__ outp, int r0, int r1, int Wp) {
    __shared__ float s[NPB * HDIM];  // 12.8 KB

    const int bin = blockIdx.x;
    for (int i = threadIdx.x; i < NPB * HDIM; i += 256) s[i] = 0.f;
    __syncthreads();

    const int elo = ofs[bin * NUM_RELS + r0];
    const int ehi = ofs[bin * NUM_RELS + r1];
    const int gi = threadIdx.x >> 4;   // 16 groups
    const int li = threadIdx.x & 15;

    for (int e = elo + gi; e < ehi; e += 16) {
        unsigned u = epack[e];
        int src = (int)(u & 0x1ffffu);
        int rel = (int)((u >> 17) & 31u);
        int dloc = (int)((u >> 22) & 63u);
        ushort4 q = *(const ushort4*)(hw + (size_t)src * Wp + (rel - r0) * 64 + (li << 2));
        float* p = &s[(dloc << 6) + (li << 2)];
        atomicAdd(p + 0, bf2f(q.x));
        atomicAdd(p + 1, bf2f(q.y));
        atomicAdd(p + 2, bf2f(q.z));
        atomicAdd(p + 3, bf2f(q.w));
    }
    __syncthreads();

    for (int i = threadIdx.x; i < NPB * HDIM; i += 256) {
        float v = s[i];
        int gidx = bin * NPB * HDIM + i;
        if (!FIRST) v += aggG[gidx];
        if (OUT == 0) {
            aggG[gidx] = v;
        } else {
            float inv = 1.0f / fmaxf(deg[bin * NPB + (i >> 6)], 1.0f);
            v = fmaxf(v * inv, 0.0f);
            if (OUT == 1) ((unsigned short*)outp)[gidx] = f2bf(v);
            else          ((float*)outp)[gidx] = v;
        }
    }
}

static inline size_t align_up(size_t x, size_t a) { return (x + a - 1) & ~(a - 1); }

extern "C" void kernel_launch(void* const* d_in, const int* in_sizes, int n_in,
                              void* d_out, int out_size, void* d_ws, size_t ws_size,
                              hipStream_t stream) {
    const float* h = (const float*)d_in[0];
    const int* src = (const int*)d_in[1];
    const int* dst = (const int*)d_in[2];
    const int* rel = (const int*)d_in[3];
    const float* W1 = (const float*)d_in[4];
    const float* W2 = (const float*)d_in[5];
    float* out = (float*)d_out;

    // ---- workspace layout ----
    char* w = (char*)d_ws;
    size_t off = 0;
    unsigned* epack = (unsigned*)(w + off); off = align_up(off + (size_t)N_EDGES * 4, 256);
    int* cnt  = (int*)(w + off); off = align_up(off + (size_t)(NKEYS + 4) * 4, 256);
    int* ofs  = (int*)(w + off); off = align_up(off + (size_t)(NKEYS + 8) * 4, 256);
    int* ofs2 = (int*)(w + off); off = align_up(off + (size_t)(NKEYS + 4) * 4, 256);
    int* bsum = (int*)(w + off); off = align_up(off + 192 * 4, 256);
    int* bbase= (int*)(w + off); off = align_up(off + 192 * 4, 256);
    float* deg = (float*)(w + off); off = align_up(off + (size_t)N_NODES * 4, 256);
    unsigned short* hb  = (unsigned short*)(w + off); off = align_up(off + (size_t)N_NODES * HDIM * 2, 256);
    unsigned short* h1b = (unsigned short*)(w + off); off = align_up(off + (size_t)N_NODES * HDIM * 2, 256);
    unsigned short* Bt1 = (unsigned short*)(w + off); off = align_up(off + (size_t)NCOLS * HDIM * 2, 256);
    unsigned short* Bt2 = (unsigned short*)(w + off); off = align_up(off + (size_t)NCOLS * HDIM * 2, 256);
    unsigned short* hw = (unsigned short*)(w + off);

    // ---- pick relation-split so hw fits the remaining workspace ----
    const int choices[8] = {1, 2, 3, 4, 6, 8, 12, 24};
    int ns = 24;
    for (int c = 0; c < 8; ++c) {
        size_t need = off + (size_t)N_NODES * (NCOLS / choices[c]) * 2;
        if (need <= ws_size) { ns = choices[c]; break; }
    }
    const int Wp = NCOLS / ns;
    const int RPP = NUM_RELS / ns;
    float* aggG = (float*)d_out;  // d_out doubles as cross-pass accumulator

    hipMemsetAsync(cnt, 0, (size_t)(NKEYS + 4) * 4, stream);
    hipMemsetAsync(deg, 0, (size_t)N_NODES * 4, stream);

    // ---- prep + counting sort by (dst-bin, rel) ----
    prep_h<<<(N_NODES * HDIM / 4 + 255) / 256, 256, 0, stream>>>(h, hb);
    prep_w<<<(NCOLS * HDIM + 255) / 256, 256, 0, stream>>>(W1, W2, Bt1, Bt2);
    hist_kernel<<<1024, 256, 0, stream>>>(dst, rel, cnt, deg);
    scan1<<<188, 256, 0, stream>>>(cnt, bsum);
    scan2<<<1, 64, 0, stream>>>(bsum, bbase, ofs);
    scan3<<<188, 256, 0, stream>>>(cnt, bbase, ofs, ofs2);
    scatter_kernel<<<1024, 256, 0, stream>>>(src, dst, rel, ofs2, epack);

    // ---- two layers, ns passes each ----
    for (int layer = 0; layer < 2; ++layer) {
        const unsigned short* Ain = layer ? h1b : hb;
        const unsigned short* Bt = layer ? Bt2 : Bt1;
        void* outp = layer ? (void*)out : (void*)h1b;
        for (int p = 0; p < ns; ++p) {
            int r0 = p * RPP, r1 = r0 + RPP;
            gemm_kernel<<<N_NODES / 16, 256, 0, stream>>>(Ain, Bt, hw, r0, Wp);
            bool first = (p == 0), last = (p == ns - 1);
            if (first && last) {
                if (layer) agg_kernel<true, 2><<<NBINS, 256, 0, stream>>>(hw, epack, ofs, deg, aggG, outp, r0, r1, Wp);
                else       agg_kernel<true, 1><<<NBINS, 256, 0, stream>>>(hw, epack, ofs, deg, aggG, outp, r0, r1, Wp);
            } else if (first) {
                agg_kernel<true, 0><<<NBINS, 256, 0, stream>>>(hw, epack, ofs, deg, aggG, outp, r0, r1, Wp);
            } else if (!last) {
                agg_kernel<false, 0><<<NBINS, 256, 0, stream>>>(hw, epack, ofs, deg, aggG, outp, r0, r1, Wp);
            } else {
                if (layer) agg_kernel<false, 2><<<NBINS, 256, 0, stream>>>(hw, epack, ofs, deg, aggG, outp, r0, r1, Wp);
                else       agg_kernel<false, 1><<<NBINS, 256, 0, stream>>>(hw, epack, ofs, deg, aggG, outp, r0, r1, Wp);
            }
        }
    }
}